// Round 4
// baseline (285.006 us; speedup 1.0000x reference)
//
#include <hip/hip_runtime.h>
#include <stdint.h>

// LSTM fused: B=8192, T=128, I=32, H=64, OUT=8. fp32 internal state, bf16 MFMA.
// R12 = R11's PASSING source with ONE structural change: B_TILE 16 -> 8,
// grid 512 -> 1024, 4 blocks/CU (was 2). Real batches occupy C/D rows
// {q*4+0, q*4+1} only -> gate r-loop is r in {0,1} for ALL lanes (uniform,
// per-wave trans 40->20, no divergence). MFMA stays 16x16x32 with 8 garbage
// A-rows (row-self-contained, discarded). LDS ~31KB -> 4 blocks/CU.
// Rationale: 2550 cyc/step vs ~1000 issue cyc/SIMD -> latency-bound with only
// 2 independent chains/SIMD; this doubles chains/SIMD WITHOUT widening the
// barrier (R9's failure) or duplicating VALU/trans work.
// R11 ledger: x-MFMA pipeline works ONLY as {loads hoisted to step top,
// accx MFMAs sunk after gates}; R10 proved bank conflicts are off-path
// (HPAD=144 known-good, 16B-aligned). R9: do not widen blocks to 8 waves.
// NaN ledger: R1/R5/R7 (vector weight loads, plain body) and R6 (K=16 f16)
// all NaN'd; R2/R3/R8/R11 (scalar loads + sniff dispatcher) passed. Do not
// reintroduce those factors without an isolated A/B.

#define T_STEPS 128
#define ISZ 32
#define HSZ 64
#define B_TOT 8192
#define B_TILE 8
#define BROWS 16
#define T_CHUNK 32
#define HPAD 144

typedef short bf16x8 __attribute__((ext_vector_type(8)));
typedef float f32x4 __attribute__((ext_vector_type(4)));

#define LOG2E 1.44269504088896340736f

__device__ __forceinline__ float bf2f(unsigned short s) {
    union { unsigned int u; float f; } v; v.u = ((unsigned int)s) << 16; return v.f;
}
__device__ __forceinline__ unsigned short f2bf(float f) {
    union { float f; unsigned int u; } v; v.f = f;
    unsigned int u = v.u;
    return (unsigned short)((u + 0x7fffu + ((u >> 16) & 1u)) >> 16);  // RNE
}
// sigmoid = rcp(1 + exp2(-x*log2e)); x->-inf: exp2->inf, rcp->0; x->+inf: 1. Safe.
__device__ __forceinline__ float sigf(float x) {
    return __builtin_amdgcn_rcpf(1.0f + __builtin_amdgcn_exp2f(-LOG2E * x));
}
// tanh = 1 - 2*rcp(1 + exp2(2x*log2e)); +inf -> 1; -inf -> -1. Safe.
__device__ __forceinline__ float tanh_fast(float x) {
    return 1.0f - 2.0f * __builtin_amdgcn_rcpf(1.0f + __builtin_amdgcn_exp2f((2.0f * LOG2E) * x));
}

template <bool F32>
__device__ __forceinline__ float ldin(const void* p, size_t i) {
    if (F32) return ((const float*)p)[i];
    return bf2f(((const unsigned short*)p)[i]);
}

template <bool F32>
__device__ __forceinline__ void run_body(
    const void* xv, const void* Wihv, const void* Whhv, const void* bihv,
    const void* bhhv, const void* Wfcv, const void* bfcv, void* outv,
    unsigned short (&hbuf)[2][BROWS][HPAD],
    unsigned short (&xbuf)[T_CHUNK][B_TILE][40],
    float (&hfin)[B_TILE][HSZ + 4])
{
    const int tid  = threadIdx.x;
    const int wid  = tid >> 6;
    const int lane = tid & 63;
    const int q    = lane >> 4;   // A/B frag k-quad; C/D row-quad
    const int tn   = lane & 15;   // A: batch row m; B/C: unit col n
    const int u    = wid * 16 + tn;
    const int b0   = blockIdx.x * B_TILE;
    // batch slot this lane's A-row tn would hold (valid when (tn&2)==0;
    // invalid rows duplicate a neighbor's x / read zero h -> discarded C rows)
    const int jx   = ((tn >> 2) << 1) | (tn & 1);

    // B-operand weight frags, loaded once (scalar loads — see NaN ledger).
    bf16x8 wf[4][3];
    f32x4 biasC[4];   // bias broadcast into a C-operand vector: no acc-init movs
    #pragma unroll
    for (int g = 0; g < 4; ++g) {
        const int row = g * HSZ + u;
        #pragma unroll
        for (int j = 0; j < 8; ++j) {
            wf[g][0][j] = (short)f2bf(ldin<F32>(Whhv, row * HSZ + q * 8 + j));
            wf[g][1][j] = (short)f2bf(ldin<F32>(Whhv, row * HSZ + 32 + q * 8 + j));
            wf[g][2][j] = (short)f2bf(ldin<F32>(Wihv, row * ISZ + q * 8 + j));
        }
        const float b = ldin<F32>(bihv, row) + ldin<F32>(bhhv, row);
        #pragma unroll
        for (int e = 0; e < 4; ++e) biasC[g][e] = b;
    }

    // h(0) = 0 (all 16 rows; unused rows stay zero forever)
    for (int i = tid; i < 2 * BROWS * HPAD; i += 256) ((unsigned short*)hbuf)[i] = 0;

    float cst[2] = {0.f, 0.f};
    float hl[2]  = {0.f, 0.f};
    f32x4 accx[4];

    for (int tc = 0; tc < T_STEPS / T_CHUNK; ++tc) {
        // stage x[b0..+8)[tc*32..+32)[0..32) -> xbuf[t][j][k]; prev chunk's
        // reads finished at the last step's barrier, so no barrier needed here.
        if (F32) {
            const float* xf = (const float*)xv;
            for (int idx = tid; idx < B_TILE * T_CHUNK * 4; idx += 256) {
                const int m  = idx >> 7;
                const int rm = idx & 127;
                const int tl = rm >> 2;
                const int ch = rm & 3;
                const size_t base = ((size_t)(b0 + m) * T_STEPS + (tc * T_CHUNK + tl)) * ISZ + ch * 8;
                const f32x4 v0 = *(const f32x4*)(xf + base);
                const f32x4 v1 = *(const f32x4*)(xf + base + 4);
                bf16x8 w;
                #pragma unroll
                for (int j = 0; j < 4; ++j) {
                    w[j]     = (short)f2bf(v0[j]);
                    w[4 + j] = (short)f2bf(v1[j]);
                }
                *(bf16x8*)&xbuf[tl][m][ch * 8] = w;
            }
        } else {
            const unsigned short* xu = (const unsigned short*)xv;
            for (int idx = tid; idx < B_TILE * T_CHUNK * 4; idx += 256) {
                const int m  = idx >> 7;
                const int rm = idx & 127;
                const int tl = rm >> 2;
                const int ch = rm & 3;
                const uint4 v = *(const uint4*)(xu + ((size_t)(b0 + m) * T_STEPS + (tc * T_CHUNK + tl)) * ISZ + ch * 8);
                *(uint4*)&xbuf[tl][m][ch * 8] = v;
            }
        }
        __syncthreads();

        // chunk prologue: x-contribution of step tl=0 (bias as C-operand).
        {
            const bf16x8 ax = *(const bf16x8*)&xbuf[0][jx][q * 8];
            #pragma unroll
            for (int g = 0; g < 4; ++g)
                accx[g] = __builtin_amdgcn_mfma_f32_16x16x32_bf16(ax, wf[g][2], biasC[g], 0, 0, 0);
        }

        #pragma unroll 2
        for (int tl = 0; tl < T_CHUNK; ++tl) {
            const int t  = tc * T_CHUNK + tl;
            const int rb = t & 1, wb = rb ^ 1;
            // issue ALL step loads together: h A-frags + next step's x frag.
            // ax2's lgkm wait is deferred to its first use (accx MFMAs, last).
            const bf16x8 a0  = *(const bf16x8*)&hbuf[rb][tn][q * 8];       // h k0..31
            const bf16x8 a1  = *(const bf16x8*)&hbuf[rb][tn][32 + q * 8];  // h k32..63
            const bf16x8 ax2 = *(const bf16x8*)&xbuf[(tl + 1) & (T_CHUNK - 1)][jx][q * 8];

            f32x4 acc[4];
            #pragma unroll
            for (int g = 0; g < 4; ++g)
                acc[g] = __builtin_amdgcn_mfma_f32_16x16x32_bf16(a0, wf[g][0], accx[g], 0, 0, 0);
            #pragma unroll
            for (int g = 0; g < 4; ++g)
                acc[g] = __builtin_amdgcn_mfma_f32_16x16x32_bf16(a1, wf[g][1], acc[g], 0, 0, 0);

            // gate trans phase first (issue-dominant burst); r in {0,1} only —
            // real batches live in C/D rows {q*4, q*4+1}, batch j = q*2+r.
            #pragma unroll
            for (int rr = 0; rr < 2; ++rr) {
                const float gi = sigf(acc[0][rr]);
                const float gf = sigf(acc[1][rr]);
                const float gg = tanh_fast(acc[2][rr]);
                const float go = sigf(acc[3][rr]);
                cst[rr] = gf * cst[rr] + gi * gg;
                const float hv = go * tanh_fast(cst[rr]);
                hl[rr] = hv;
                const int m = q * 4 + rr;  // C/D row = A row for batch q*2+rr
                hbuf[wb][m][u] = f2bf(hv);
            }

            // next step's x-contribution LAST: fills the write/barrier window.
            // (tl+1)&31 wraps to stale xbuf[0] on the last step; that accx is
            // discarded (next chunk's prologue recomputes from fresh data),
            // and the read precedes the staging barrier -> no race.
            #pragma unroll
            for (int g = 0; g < 4; ++g)
                accx[g] = __builtin_amdgcn_mfma_f32_16x16x32_bf16(ax2, wf[g][2], biasC[g], 0, 0, 0);

            __syncthreads();
        }
    }

    // epilogue: out[b][j] = h_T(fp32) . Wfc[j,:] + bfc[j]
    #pragma unroll
    for (int rr = 0; rr < 2; ++rr) hfin[q * 2 + rr][u] = hl[rr];
    __syncthreads();
    if (tid < B_TILE * 8) {
        const int m = tid >> 3, j = tid & 7;
        float s = ldin<F32>(bfcv, j);
        #pragma unroll
        for (int k = 0; k < HSZ; ++k) s += hfin[m][k] * ldin<F32>(Wfcv, j * HSZ + k);
        const size_t o = (size_t)(b0 + m) * 8 + j;
        if (F32) ((float*)outv)[o] = s;
        else     ((unsigned short*)outv)[o] = f2bf(s);
    }
}

__global__ __launch_bounds__(256, 4) void lstm_fused(
    const void* __restrict__ x, const void* __restrict__ Wih,
    const void* __restrict__ Whh, const void* __restrict__ bih,
    const void* __restrict__ bhh, const void* __restrict__ Wfc,
    const void* __restrict__ bfc, void* __restrict__ out)
{
    __shared__ unsigned short hbuf[2][BROWS][HPAD];
    __shared__ unsigned short xbuf[T_CHUNK][B_TILE][40];
    __shared__ float hfin[B_TILE][HSZ + 4];

    // dtype sniff (guard): fp32 data read as uint16 halves has mantissa-garbage
    // halves decoding to huge-exponent bf16s; real bf16 data never exceeds 2^17.
    const unsigned short* xu = (const unsigned short*)x;
    const int lane = threadIdx.x & 63;
    const unsigned short s0 = xu[lane * 2];
    const unsigned short s1 = xu[lane * 2 + 1];
    const int big = (((s0 >> 7) & 0xFF) >= 0x90) || (((s1 >> 7) & 0xFF) >= 0x90);
    const bool isf32 = __any(big) != 0;

    if (isf32) run_body<true >(x, Wih, Whh, bih, bhh, Wfc, bfc, out, hbuf, xbuf, hfin);
    else       run_body<false>(x, Wih, Whh, bih, bhh, Wfc, bfc, out, hbuf, xbuf, hfin);
}

extern "C" void kernel_launch(void* const* d_in, const int* in_sizes, int n_in,
                              void* d_out, int out_size, void* d_ws, size_t ws_size,
                              hipStream_t stream) {
    lstm_fused<<<dim3(B_TOT / B_TILE), dim3(256), 0, stream>>>(
        d_in[0], d_in[1], d_in[2], d_in[3], d_in[4], d_in[5], d_in[6], d_out);
}